// Round 3
// baseline (529.157 us; speedup 1.0000x reference)
//
#include <hip/hip_runtime.h>
#include <cstdint>
#include <cstddef>

// Problem constants (fixed by the reference)
#define N_NODES 10000
#define F_IN    512
#define NHID    32
#define LATENT  16

typedef float v2f __attribute__((ext_vector_type(2)));

// ---------------------------------------------------------------------------
// Scratch layout inside d_out's adjacency region (overwritten by the decoder
// last). All offsets in floats, 16-float aligned. Total ~5.9 MB << 400 MB.
// ---------------------------------------------------------------------------
#define OF_H0   0              // [N,32] f32
#define OF_H    320000         // [N,32] f32
#define OF_Z0   640000         // [N,16] f32
#define OF_DEG  800000         // [10240] i32 (zeroed each call)
#define OF_RP   810240         // [10241] i32 row_ptr
#define OF_CUR  820496         // [10241] i32 cursor
#define OF_ESW  830752         // [E] int2 (src, bits(w))  — even offset -> 8B aligned

// ---------------------------------------------------------------------------
// CSR build step 1: degree histogram over dst
// ---------------------------------------------------------------------------
__global__ __launch_bounds__(256) void hist_kernel(const int* __restrict__ dst,
                                                   int* __restrict__ deg, int E) {
    const int e = blockIdx.x * 256 + threadIdx.x;
    if (e < E) atomicAdd(&deg[dst[e]], 1);
}

// ---------------------------------------------------------------------------
// CSR build step 2: single-block exclusive scan of deg[0..10239] -> row_ptr,
// cursor. 1024 threads x 10 elements each.
// ---------------------------------------------------------------------------
__global__ __launch_bounds__(1024) void scan_kernel(const int* __restrict__ deg,
                                                    int* __restrict__ row_ptr,
                                                    int* __restrict__ cursor) {
    __shared__ int sums[1024];
    const int tid = threadIdx.x;
    const int base = tid * 10;
    int local[10];
    int s = 0;
#pragma unroll
    for (int i = 0; i < 10; ++i) { local[i] = s; s += deg[base + i]; }
    sums[tid] = s;
    __syncthreads();
    // Hillis-Steele inclusive scan
    for (int off = 1; off < 1024; off <<= 1) {
        int v = (tid >= off) ? sums[tid - off] : 0;
        __syncthreads();
        sums[tid] += v;
        __syncthreads();
    }
    const int excl = (tid == 0) ? 0 : sums[tid - 1];
#pragma unroll
    for (int i = 0; i < 10; ++i) {
        const int g = base + i;
        if (g <= N_NODES) {  // need row_ptr[N] too
            const int rp = excl + local[i];
            row_ptr[g] = rp;
            cursor[g]  = rp;
        }
    }
}

// ---------------------------------------------------------------------------
// CSR build step 3: scatter edges into dst buckets as (src, bits(w))
// ---------------------------------------------------------------------------
__global__ __launch_bounds__(256) void scatter_kernel(const int* __restrict__ src,
                                                      const int* __restrict__ dst,
                                                      const float* __restrict__ w,
                                                      int* __restrict__ cursor,
                                                      int2* __restrict__ esw, int E) {
    const int e = blockIdx.x * 256 + threadIdx.x;
    if (e < E) {
        const int d = dst[e];
        const int pos = atomicAdd(&cursor[d], 1);
        esw[pos] = make_int2(src[e], __float_as_int(w[e]));
    }
}

// ---------------------------------------------------------------------------
// GEMM1: h0 = x @ W1  [10000,512]x[512,32]. Block = 256 thr = 32 rows x
// (8 col-groups of 4). W1 in LDS (2 chunks of 32KB); x rows read as float4
// straight from global (8-lane same-address broadcast, L1-resident).
// 4 FMA per ds_read_b128 -> not LDS-issue bound.
// ---------------------------------------------------------------------------
#define G1_KC 256
__global__ __launch_bounds__(256) void gemm1_kernel(const float* __restrict__ x,
                                                    const float* __restrict__ W1,
                                                    float* __restrict__ h0) {
    __shared__ float w1s[G1_KC * NHID];  // 32 KB
    const int row0 = blockIdx.x * 32;
    const int rp   = threadIdx.x >> 3;        // 0..31: row
    const int cg   = (threadIdx.x & 7) * 4;   // col group base
    const int gr   = min(row0 + rp, N_NODES - 1);  // clamp (last block)
    const float4* __restrict__ xrow = (const float4*)(x + (size_t)gr * F_IN);

    float4 acc = make_float4(0.f, 0.f, 0.f, 0.f);

    for (int kc = 0; kc < F_IN; kc += G1_KC) {
        // stage W1 chunk: 8192 floats, 32 consecutive per thread
        {
            const float4* __restrict__ wg = (const float4*)(W1 + (size_t)kc * NHID);
            float4* __restrict__ ws4 = (float4*)w1s;
            const int b = threadIdx.x * 8;
#pragma unroll
            for (int i = 0; i < 8; ++i) ws4[b + i] = wg[b + i];
        }
        __syncthreads();

        const int k4base = kc >> 2;
#pragma unroll 4
        for (int kk4 = 0; kk4 < G1_KC / 4; ++kk4) {
            const float4 xv = xrow[k4base + kk4];
            const float4 w0 = *(const float4*)&w1s[(kk4 * 4 + 0) * NHID + cg];
            const float4 w1 = *(const float4*)&w1s[(kk4 * 4 + 1) * NHID + cg];
            const float4 w2 = *(const float4*)&w1s[(kk4 * 4 + 2) * NHID + cg];
            const float4 w3 = *(const float4*)&w1s[(kk4 * 4 + 3) * NHID + cg];
            acc.x += xv.x * w0.x + xv.y * w1.x + xv.z * w2.x + xv.w * w3.x;
            acc.y += xv.x * w0.y + xv.y * w1.y + xv.z * w2.y + xv.w * w3.y;
            acc.z += xv.x * w0.z + xv.y * w1.z + xv.z * w2.z + xv.w * w3.z;
            acc.w += xv.x * w0.w + xv.y * w1.w + xv.z * w2.w + xv.w * w3.w;
        }
        __syncthreads();
    }

    if (row0 + rp < N_NODES) {
        *(float4*)&h0[(size_t)(row0 + rp) * NHID + cg] = acc;
    }
}

// ---------------------------------------------------------------------------
// Gather SpMM: hout[n][d] = sum_{p in row_ptr[n]..row_ptr[n+1]} w_p*hin[src_p][d]
// No atomics, deterministic, L2-resident. D-lane groups share the edge loads.
// ---------------------------------------------------------------------------
template <int D>
__global__ __launch_bounds__(256) void gather_kernel(const int* __restrict__ row_ptr,
                                                     const int2* __restrict__ esw,
                                                     const float* __restrict__ hin,
                                                     float* __restrict__ hout) {
    const int idx = blockIdx.x * 256 + threadIdx.x;
    const int n = idx / D;
    const int d = idx & (D - 1);
    if (n >= N_NODES) return;
    const int beg = row_ptr[n];
    const int end = row_ptr[n + 1];
    float acc = 0.f;
    int p = beg;
    for (; p + 1 < end; p += 2) {
        const int2 e0 = esw[p];
        const int2 e1 = esw[p + 1];
        acc += __int_as_float(e0.y) * hin[(size_t)e0.x * D + d];
        acc += __int_as_float(e1.y) * hin[(size_t)e1.x * D + d];
    }
    if (p < end) {
        const int2 e0 = esw[p];
        acc += __int_as_float(e0.y) * hin[(size_t)e0.x * D + d];
    }
    hout[(size_t)n * D + d] = acc;
}

// ---------------------------------------------------------------------------
// GEMM2: z0 = h @ W2  [10000,32]x[32,16]; one thread per output element.
// ---------------------------------------------------------------------------
__global__ __launch_bounds__(256) void gemm2_kernel(const float* __restrict__ h,
                                                    const float* __restrict__ W2,
                                                    float* __restrict__ z0) {
    __shared__ float w2s[NHID * LATENT];
    for (int t = threadIdx.x; t < NHID * LATENT; t += 256) w2s[t] = W2[t];
    __syncthreads();

    const int idx = blockIdx.x * 256 + threadIdx.x;
    if (idx < N_NODES * LATENT) {
        const int row = idx >> 4;
        const int col = idx & (LATENT - 1);
        const float4* __restrict__ hr = (const float4*)(h + (size_t)row * NHID);
        float acc = 0.f;
#pragma unroll
        for (int k4 = 0; k4 < NHID / 4; ++k4) {
            const float4 hv = hr[k4];
            acc += hv.x * w2s[(k4 * 4 + 0) * LATENT + col]
                 + hv.y * w2s[(k4 * 4 + 1) * LATENT + col]
                 + hv.z * w2s[(k4 * 4 + 2) * LATENT + col]
                 + hv.w * w2s[(k4 * 4 + 3) * LATENT + col];
        }
        z0[idx] = acc;
    }
}

// ---------------------------------------------------------------------------
// Decoder: out[i][j] = sigmoid(dot(z[i], z[j])). Thread owns 2 consecutive
// j-columns (z[j] pair in 32 VGPRs), block covers TI=40 i-rows (250 y-blocks,
// no i-tail). zi loads are wave-uniform (blockIdx-only) -> scalarized.
// float2 nontemporal stores; HBM-write bound (400 MB ~= 63 us floor).
// ---------------------------------------------------------------------------
#define TI 40

__device__ __forceinline__ float sigmoid_fast(float x) {
    return __builtin_amdgcn_rcpf(1.0f + __expf(-x));
}

__global__ __launch_bounds__(256) void decoder_kernel(const float* __restrict__ z,
                                                      float* __restrict__ out) {
    const int j0 = (blockIdx.x * 256 + threadIdx.x) * 2;
    const int i0 = blockIdx.y * TI;

    float4 a0, a1, a2, a3, b0, b1, b2, b3;
    if (j0 < N_NODES) {
        const float4* __restrict__ zp = (const float4*)(z + (size_t)j0 * LATENT);
        a0 = zp[0]; a1 = zp[1]; a2 = zp[2]; a3 = zp[3];
        b0 = zp[4]; b1 = zp[5]; b2 = zp[6]; b3 = zp[7];
    } else {
        a0 = a1 = a2 = a3 = make_float4(0.f, 0.f, 0.f, 0.f);
        b0 = b1 = b2 = b3 = a0;
    }

#pragma unroll 4
    for (int ii = 0; ii < TI; ++ii) {
        const int i = i0 + ii;
        const float4* __restrict__ zi = (const float4*)(z + (size_t)i * LATENT);
        const float4 c0 = zi[0], c1 = zi[1], c2 = zi[2], c3 = zi[3];
        const float s0 = c0.x * a0.x + c0.y * a0.y + c0.z * a0.z + c0.w * a0.w
                       + c1.x * a1.x + c1.y * a1.y + c1.z * a1.z + c1.w * a1.w
                       + c2.x * a2.x + c2.y * a2.y + c2.z * a2.z + c2.w * a2.w
                       + c3.x * a3.x + c3.y * a3.y + c3.z * a3.z + c3.w * a3.w;
        const float s1 = c0.x * b0.x + c0.y * b0.y + c0.z * b0.z + c0.w * b0.w
                       + c1.x * b1.x + c1.y * b1.y + c1.z * b1.z + c1.w * b1.w
                       + c2.x * b2.x + c2.y * b2.y + c2.z * b2.z + c2.w * b2.w
                       + c3.x * b3.x + c3.y * b3.y + c3.z * b3.z + c3.w * b3.w;
        if (j0 < N_NODES) {
            v2f r;
            r.x = sigmoid_fast(s0);
            r.y = sigmoid_fast(s1);
            __builtin_nontemporal_store(r, (v2f*)(out + (size_t)i * N_NODES + j0));
        }
    }
}

// ---------------------------------------------------------------------------
extern "C" void kernel_launch(void* const* d_in, const int* in_sizes, int n_in,
                              void* d_out, int out_size, void* d_ws, size_t ws_size,
                              hipStream_t stream) {
    const float* x  = (const float*)d_in[0];   // [N, 512]
    const float* W1 = (const float*)d_in[1];   // [512, 32]
    const float* W2 = (const float*)d_in[2];   // [32, 16]
    const int*   ei = (const int*)d_in[3];     // [2, E]
    const float* ew = (const float*)d_in[4];   // [E]
    const int E = in_sizes[3] / 2;
    const int* src = ei;
    const int* dst = ei + E;

    float* out = (float*)d_out;                          // [N, N]
    float* z   = out + (size_t)N_NODES * N_NODES;        // [N, 16] final tail

    float* h0     = out + OF_H0;
    float* h      = out + OF_H;
    float* z0     = out + OF_Z0;
    int*   deg    = (int*)(out + OF_DEG);
    int*   rowp   = (int*)(out + OF_RP);
    int*   cursor = (int*)(out + OF_CUR);
    int2*  esw    = (int2*)(out + OF_ESW);

    // CSR build (reused by both layers)
    hipMemsetAsync(deg, 0, 10240 * sizeof(int), stream);
    hist_kernel<<<(E + 255) / 256, 256, 0, stream>>>(dst, deg, E);
    scan_kernel<<<1, 1024, 0, stream>>>(deg, rowp, cursor);
    scatter_kernel<<<(E + 255) / 256, 256, 0, stream>>>(src, dst, ew, cursor, esw, E);

    // layer 1: h = A @ (x @ W1)
    gemm1_kernel<<<(N_NODES + 31) / 32, 256, 0, stream>>>(x, W1, h0);
    gather_kernel<NHID><<<(N_NODES * NHID + 255) / 256, 256, 0, stream>>>(rowp, esw, h0, h);

    // layer 2: z = A @ (h @ W2)
    gemm2_kernel<<<(N_NODES * LATENT + 255) / 256, 256, 0, stream>>>(h, W2, z0);
    gather_kernel<LATENT><<<(N_NODES * LATENT + 255) / 256, 256, 0, stream>>>(rowp, esw, z0, z);

    // decoder: adj_recon = sigmoid(z @ z^T)
    dim3 dgrid((N_NODES / 2 + 255) / 256, N_NODES / TI);
    decoder_kernel<<<dgrid, 256, 0, stream>>>(z, out);
}

// Round 4
// 511.970 us; speedup vs baseline: 1.0336x; 1.0336x over previous
//
#include <hip/hip_runtime.h>
#include <cstdint>
#include <cstddef>

// Problem constants (fixed by the reference)
#define N_NODES 10000
#define F_IN    512
#define NHID    32
#define LATENT  16

typedef float v4f __attribute__((ext_vector_type(4)));

// Scratch layout inside d_out's adjacency region (decoder overwrites it last).
#define OF_H0   0              // [N,32] f32
#define OF_H    320000         // [N,32] f32

// ---------------------------------------------------------------------------
// D1: gemm1 (h0 = x @ W1) + zero h,z.
// gemm blocks: 313 tiles of 32 rows; block = 256 thr = 32 rows x 8 col-groups.
// W1 staged in LDS (2 chunks of 32 KB). x rows read as float4 from global.
// zero blocks (blockIdx >= 313): grid-stride float4 memset of h and z.
// ---------------------------------------------------------------------------
#define G1_TILES 313
#define ZERO_BLOCKS 64
#define G1_KC 256

__global__ __launch_bounds__(256) void stage1_kernel(const float* __restrict__ x,
                                                     const float* __restrict__ W1,
                                                     float* __restrict__ h0,
                                                     float* __restrict__ h,
                                                     float* __restrict__ z) {
    __shared__ float w1s[G1_KC * NHID];  // 32 KB

    if (blockIdx.x >= G1_TILES) {
        // ---- zeroing path: h (320k floats) + z (160k floats) ----
        const int tid = (blockIdx.x - G1_TILES) * 256 + threadIdx.x;
        const int nthr = ZERO_BLOCKS * 256;
        float4* __restrict__ h4 = (float4*)h;
        float4* __restrict__ z4 = (float4*)z;
        const v4f zero = {0.f, 0.f, 0.f, 0.f};
        for (int i = tid; i < (N_NODES * NHID) / 4; i += nthr)
            *(v4f*)&h4[i] = zero;
        for (int i = tid; i < (N_NODES * LATENT) / 4; i += nthr)
            *(v4f*)&z4[i] = zero;
        return;
    }

    const int row0 = blockIdx.x * 32;
    const int rp   = threadIdx.x >> 3;        // 0..31: row
    const int cg   = (threadIdx.x & 7) * 4;   // col group base
    const int gr   = min(row0 + rp, N_NODES - 1);  // clamp (last block)
    const float4* __restrict__ xrow = (const float4*)(x + (size_t)gr * F_IN);

    float4 acc = make_float4(0.f, 0.f, 0.f, 0.f);

    for (int kc = 0; kc < F_IN; kc += G1_KC) {
        {
            const float4* __restrict__ wg = (const float4*)(W1 + (size_t)kc * NHID);
            float4* __restrict__ ws4 = (float4*)w1s;
            const int b = threadIdx.x * 8;
#pragma unroll
            for (int i = 0; i < 8; ++i) ws4[b + i] = wg[b + i];
        }
        __syncthreads();

        const int k4base = kc >> 2;
#pragma unroll 4
        for (int kk4 = 0; kk4 < G1_KC / 4; ++kk4) {
            const float4 xv = xrow[k4base + kk4];
            const float4 w0 = *(const float4*)&w1s[(kk4 * 4 + 0) * NHID + cg];
            const float4 w1 = *(const float4*)&w1s[(kk4 * 4 + 1) * NHID + cg];
            const float4 w2 = *(const float4*)&w1s[(kk4 * 4 + 2) * NHID + cg];
            const float4 w3 = *(const float4*)&w1s[(kk4 * 4 + 3) * NHID + cg];
            acc.x += xv.x * w0.x + xv.y * w1.x + xv.z * w2.x + xv.w * w3.x;
            acc.y += xv.x * w0.y + xv.y * w1.y + xv.z * w2.y + xv.w * w3.y;
            acc.z += xv.x * w0.z + xv.y * w1.z + xv.z * w2.z + xv.w * w3.z;
            acc.w += xv.x * w0.w + xv.y * w1.w + xv.z * w2.w + xv.w * w3.w;
        }
        __syncthreads();
    }

    if (row0 + rp < N_NODES) {
        *(float4*)&h0[(size_t)(row0 + rp) * NHID + cg] = acc;
    }
}

// ---------------------------------------------------------------------------
// D2: scatter SpMM layer 1:  h[dst[e]][d] += w[e] * h0[src[e]][d], D=32.
// One thread per (edge, feature); wave covers 2 edges -> edge loads dedup in
// the coalescer, h0 row reads are 128 B coalesced per 32-lane group.
// ---------------------------------------------------------------------------
__global__ __launch_bounds__(256) void spmm32_kernel(const int* __restrict__ src,
                                                     const int* __restrict__ dst,
                                                     const float* __restrict__ w,
                                                     const float* __restrict__ hin,
                                                     float* __restrict__ hout,
                                                     int E) {
    const int idx = blockIdx.x * 256 + threadIdx.x;
    const int e = idx >> 5;
    const int d = idx & 31;
    if (e < E) {
        const int s = src[e];
        const int t = dst[e];
        const float val = w[e] * hin[(size_t)s * NHID + d];
        atomicAdd(&hout[(size_t)t * NHID + d], val);
    }
}

// ---------------------------------------------------------------------------
// D3: fused gemm2 + spmm layer 2:
//   z[dst[e]][d] += w[e] * dot(h[src[e]], W2[:,d]),  d in [0,16).
// W2 (512 floats) in LDS; all 64 lanes of a wave read only 16 distinct LDS
// addresses per k (broadcast, conflict-free). h row = 8 float4 loads with
// 16-lane same-address dedup. Removes the z0 materialization dispatch.
// ---------------------------------------------------------------------------
__global__ __launch_bounds__(256) void l2_fused_kernel(const int* __restrict__ src,
                                                       const int* __restrict__ dst,
                                                       const float* __restrict__ w,
                                                       const float* __restrict__ h,
                                                       const float* __restrict__ W2,
                                                       float* __restrict__ z,
                                                       int E) {
    __shared__ float w2s[NHID * LATENT];
    for (int t = threadIdx.x; t < NHID * LATENT; t += 256) w2s[t] = W2[t];
    __syncthreads();

    const int idx = blockIdx.x * 256 + threadIdx.x;
    const int e = idx >> 4;
    const int d = idx & (LATENT - 1);
    if (e < E) {
        const int s = src[e];
        const int t = dst[e];
        const float4* __restrict__ hr = (const float4*)(h + (size_t)s * NHID);
        float acc = 0.f;
#pragma unroll
        for (int k4 = 0; k4 < NHID / 4; ++k4) {
            const float4 hv = hr[k4];
            acc += hv.x * w2s[(k4 * 4 + 0) * LATENT + d]
                 + hv.y * w2s[(k4 * 4 + 1) * LATENT + d]
                 + hv.z * w2s[(k4 * 4 + 2) * LATENT + d]
                 + hv.w * w2s[(k4 * 4 + 3) * LATENT + d];
        }
        atomicAdd(&z[(size_t)t * LATENT + d], w[e] * acc);
    }
}

// ---------------------------------------------------------------------------
// D4: decoder out[i][j] = sigmoid(dot(z[i], z[j])). Thread owns 4 consecutive
// j-columns (z[j0..j0+3] = 16 float4 in VGPRs, one contiguous 256 B load),
// block covers TI=40 i-rows (250 y-blocks, no tail). zi loads are
// wave-uniform. float4 nontemporal stores; 400 MB write floor ~= 63 us.
// ---------------------------------------------------------------------------
#define TI 40

__device__ __forceinline__ float sigmoid_fast(float x) {
    return __builtin_amdgcn_rcpf(1.0f + __expf(-x));
}

__global__ __launch_bounds__(256) void decoder_kernel(const float* __restrict__ z,
                                                      float* __restrict__ out) {
    const int j0 = (blockIdx.x * 256 + threadIdx.x) * 4;
    const int i0 = blockIdx.y * TI;
    if (j0 >= N_NODES) return;

    // z rows j0..j0+3 : 16 float4
    float4 zj[4][4];
    {
        const float4* __restrict__ zp = (const float4*)(z + (size_t)j0 * LATENT);
#pragma unroll
        for (int c = 0; c < 4; ++c)
#pragma unroll
            for (int q = 0; q < 4; ++q) zj[c][q] = zp[c * 4 + q];
    }

#pragma unroll 2
    for (int ii = 0; ii < TI; ++ii) {
        const int i = i0 + ii;
        const float4* __restrict__ zi = (const float4*)(z + (size_t)i * LATENT);
        const float4 c0 = zi[0], c1 = zi[1], c2 = zi[2], c3 = zi[3];
        v4f r;
#pragma unroll
        for (int c = 0; c < 4; ++c) {
            const float s =
                  c0.x * zj[c][0].x + c0.y * zj[c][0].y + c0.z * zj[c][0].z + c0.w * zj[c][0].w
                + c1.x * zj[c][1].x + c1.y * zj[c][1].y + c1.z * zj[c][1].z + c1.w * zj[c][1].w
                + c2.x * zj[c][2].x + c2.y * zj[c][2].y + c2.z * zj[c][2].z + c2.w * zj[c][2].w
                + c3.x * zj[c][3].x + c3.y * zj[c][3].y + c3.z * zj[c][3].z + c3.w * zj[c][3].w;
            r[c] = sigmoid_fast(s);
        }
        __builtin_nontemporal_store(r, (v4f*)(out + (size_t)i * N_NODES + j0));
    }
}

// ---------------------------------------------------------------------------
extern "C" void kernel_launch(void* const* d_in, const int* in_sizes, int n_in,
                              void* d_out, int out_size, void* d_ws, size_t ws_size,
                              hipStream_t stream) {
    const float* x  = (const float*)d_in[0];   // [N, 512]
    const float* W1 = (const float*)d_in[1];   // [512, 32]
    const float* W2 = (const float*)d_in[2];   // [32, 16]
    const int*   ei = (const int*)d_in[3];     // [2, E]
    const float* ew = (const float*)d_in[4];   // [E]
    const int E = in_sizes[3] / 2;
    const int* src = ei;
    const int* dst = ei + E;

    float* out = (float*)d_out;                          // [N, N]
    float* z   = out + (size_t)N_NODES * N_NODES;        // [N, 16] final tail
    float* h0  = out + OF_H0;
    float* h   = out + OF_H;

    // D1: gemm1 + zero h,z
    stage1_kernel<<<G1_TILES + ZERO_BLOCKS, 256, 0, stream>>>(x, W1, h0, h, z);

    // D2: h = A @ h0
    spmm32_kernel<<<(E * NHID + 255) / 256, 256, 0, stream>>>(src, dst, ew, h0, h, E);

    // D3: z = A @ (h @ W2), fused
    l2_fused_kernel<<<(E * LATENT + 255) / 256, 256, 0, stream>>>(src, dst, ew, h, W2, z, E);

    // D4: adj_recon = sigmoid(z @ z^T)
    dim3 dgrid((N_NODES / 4 + 255) / 256, N_NODES / TI);
    decoder_kernel<<<dgrid, 256, 0, stream>>>(z, out);
}